// Round 1
// baseline (479.706 us; speedup 1.0000x reference)
//
#include <hip/hip_runtime.h>
#include <math.h>

#define B_  64
#define T_  2048
#define DZ_ 512
#define DC_ 256
#define K_  12
#define R_  2

// ---------------------------------------------------------------------------
// Kernel A: pred[b][k][o] = sum_d W[k][o][d] * c[b][t[b]][d] + bias[k][o]
// grid (2, 8, K): x = o-half (256 outputs), y = b-group of 8, z = k
// ---------------------------------------------------------------------------
__global__ __launch_bounds__(256) void pred_kernel(
    const float* __restrict__ c, const float* __restrict__ W,
    const float* __restrict__ bias, const int* __restrict__ t,
    float* __restrict__ pred)
{
    __shared__ float cts[8 * DC_];          // 8 KB: 8 gathered c_t rows
    const int oz = blockIdx.x;              // 0..1
    const int b0 = blockIdx.y * 8;
    const int k  = blockIdx.z;
    const int tid = threadIdx.x;

    for (int i = tid; i < 8 * DC_; i += 256) {
        int bb = i >> 8;                    // DC_ == 256
        int d  = i & 255;
        int tb = t[b0 + bb];
        cts[i] = c[((size_t)(b0 + bb) * T_ + tb) * DC_ + d];
    }
    __syncthreads();

    const int o = oz * 256 + tid;
    const float4* W4   = (const float4*)(W + ((size_t)k * DZ_ + o) * DC_);
    const float4* cts4 = (const float4*)cts;

    float acc[8];
    #pragma unroll
    for (int bb = 0; bb < 8; ++bb) acc[bb] = 0.f;

    for (int d4 = 0; d4 < DC_ / 4; ++d4) {
        float4 w = W4[d4];
        #pragma unroll
        for (int bb = 0; bb < 8; ++bb) {
            float4 cv = cts4[bb * (DC_ / 4) + d4];   // same-address broadcast
            acc[bb] += w.x * cv.x + w.y * cv.y + w.z * cv.z + w.w * cv.w;
        }
    }

    const float bv = bias[(size_t)k * DZ_ + o];
    #pragma unroll
    for (int bb = 0; bb < 8; ++bb)
        pred[((size_t)(b0 + bb) * K_ + k) * DZ_ + o] = acc[bb] + bv;
}

// ---------------------------------------------------------------------------
// Kernel B: s[k][b][row] = z[b][row] . pred[b][k]   (the 268 MB z pass)
// grid (T/64, B); block 256 = 4 waves; each wave owns 16 rows sequentially.
// Lanes cover d: lane i holds d = 4i..4i+3 and d = 256+4i..256+4i+3.
// ---------------------------------------------------------------------------
#define ROWS_PB 64
__global__ __launch_bounds__(256) void score_kernel(
    const float* __restrict__ z, const float* __restrict__ pred,
    float* __restrict__ s)
{
    __shared__ float ps[K_ * DZ_];          // 24 KB: pred[b][k][o]
    const int b   = blockIdx.y;
    const int tid = threadIdx.x;

    const float4* pg  = (const float4*)(pred + (size_t)b * K_ * DZ_);
    float4*       ps4s = (float4*)ps;
    for (int i = tid; i < K_ * DZ_ / 4; i += 256) ps4s[i] = pg[i];
    __syncthreads();

    const int wave = tid >> 6, lane = tid & 63;
    const int row0 = blockIdx.x * ROWS_PB + wave * (ROWS_PB / 4);
    const float4* ps4 = (const float4*)ps;

    for (int r = 0; r < ROWS_PB / 4; ++r) {
        const int row = row0 + r;
        const float4* zr = (const float4*)(z + ((size_t)b * T_ + row) * DZ_);
        float4 z0 = zr[lane];
        float4 z1 = zr[lane + 64];

        float acc[K_];
        #pragma unroll
        for (int k = 0; k < K_; ++k) {
            float4 p0 = ps4[k * (DZ_ / 4) + lane];
            float4 p1 = ps4[k * (DZ_ / 4) + lane + 64];
            acc[k] = z0.x * p0.x + z0.y * p0.y + z0.z * p0.z + z0.w * p0.w
                   + z1.x * p1.x + z1.y * p1.y + z1.z * p1.z + z1.w * p1.w;
        }

        #pragma unroll
        for (int k = 0; k < K_; ++k) {
            float v = acc[k];
            #pragma unroll
            for (int off = 32; off >= 1; off >>= 1)
                v += __shfl_xor(v, off, 64);
            acc[k] = v;
        }

        if (lane == 0) {
            #pragma unroll
            for (int k = 0; k < K_; ++k)
                s[((size_t)k * B_ + b) * T_ + row] = acc[k];
        }
    }
}

// ---------------------------------------------------------------------------
// Kernel C: per (k,b): lse over {pos} u {s[k,b,actual(k,b,r,j)]}, accumulate
// (lse - pos) / (K*B*R) into out. grid (K, B), block 256.
// ---------------------------------------------------------------------------
__global__ __launch_bounds__(256) void loss_kernel(
    const float* __restrict__ s, const int* __restrict__ t,
    const int* __restrict__ rand_idx, float* __restrict__ out)
{
    __shared__ float srow[T_];              // 8 KB score row
    __shared__ float red_m[4], red_l[4];
    const int k   = blockIdx.x;             // step = k+1
    const int b   = blockIdx.y;
    const int tid = threadIdx.x;

    const float4* sg = (const float4*)(s + ((size_t)k * B_ + b) * T_);
    float4* s4 = (float4*)srow;
    for (int i = tid; i < T_ / 4; i += 256) s4[i] = sg[i];
    __syncthreads();

    const int e   = t[b] + k + 1;
    const float pos = srow[e];
    float total = 0.f;

    for (int r = 0; r < R_; ++r) {
        const int* ri = rand_idx + ((size_t)k * R_ + r) * (T_ - 1);
        float m = -INFINITY, l = 0.f;
        for (int j = tid; j < T_ - 1; j += 256) {
            int idx = ri[j];
            idx += (idx >= e);              // skip the positive frame
            float v = srow[idx];
            if (v > m) { l = l * __expf(m - v) + 1.f; m = v; }
            else       { l += __expf(v - m); }
        }
        // wave butterfly combine of (m, l)
        const int lane = tid & 63, wave = tid >> 6;
        #pragma unroll
        for (int off = 32; off >= 1; off >>= 1) {
            float m2 = __shfl_xor(m, off, 64);
            float l2 = __shfl_xor(l, off, 64);
            float mn = fmaxf(m, m2);
            l = l * __expf(m - mn) + l2 * __expf(m2 - mn);
            m = mn;
        }
        if (lane == 0) { red_m[wave] = m; red_l[wave] = l; }
        __syncthreads();
        if (tid == 0) {
            float M = pos, L = 1.f;         // candidate 0 is the positive
            for (int w = 0; w < 4; ++w) {
                float m2 = red_m[w], l2 = red_l[w];
                float mn = fmaxf(M, m2);
                L = L * __expf(M - mn) + l2 * __expf(m2 - mn);
                M = mn;
            }
            total += (M + __logf(L)) - pos;
        }
        __syncthreads();
    }
    if (tid == 0)
        atomicAdd(out, total * (1.0f / (K_ * B_ * R_)));
}

// ---------------------------------------------------------------------------
extern "C" void kernel_launch(void* const* d_in, const int* in_sizes, int n_in,
                              void* d_out, int out_size, void* d_ws, size_t ws_size,
                              hipStream_t stream)
{
    const float* z        = (const float*)d_in[0];
    const float* c        = (const float*)d_in[1];
    const float* Wk_w     = (const float*)d_in[2];
    const float* Wk_b     = (const float*)d_in[3];
    const int*   t        = (const int*)d_in[4];
    const int*   rand_idx = (const int*)d_in[5];
    float* out = (float*)d_out;

    float* pred = (float*)d_ws;                        // B*K*DZ  = 1.57 MB
    float* s    = pred + (size_t)B_ * K_ * DZ_;        // K*B*T   = 6.29 MB

    hipMemsetAsync(d_out, 0, sizeof(float), stream);

    pred_kernel<<<dim3(2, 8, K_), 256, 0, stream>>>(c, Wk_w, Wk_b, t, pred);
    score_kernel<<<dim3(T_ / ROWS_PB, B_), 256, 0, stream>>>(z, pred, s);
    loss_kernel<<<dim3(K_, B_), 256, 0, stream>>>(s, t, rand_idx, out);
}

// Round 2
// 465.981 us; speedup vs baseline: 1.0295x; 1.0295x over previous
//
#include <hip/hip_runtime.h>
#include <math.h>

#define B_  64
#define T_  2048
#define DZ_ 512
#define DC_ 256
#define K_  12
#define R_  2

// ---------------------------------------------------------------------------
// Kernel A: pred[b][k][o] = sum_d W[k][o][d] * c[b][t[b]][d] + bias[k][o]
// grid (2, 8, K): x = o-half (256 outputs), y = b-group of 8, z = k
// ---------------------------------------------------------------------------
__global__ __launch_bounds__(256) void pred_kernel(
    const float* __restrict__ c, const float* __restrict__ W,
    const float* __restrict__ bias, const int* __restrict__ t,
    float* __restrict__ pred)
{
    __shared__ float cts[8 * DC_];          // 8 KB: 8 gathered c_t rows
    const int oz = blockIdx.x;              // 0..1
    const int b0 = blockIdx.y * 8;
    const int k  = blockIdx.z;
    const int tid = threadIdx.x;

    for (int i = tid; i < 8 * DC_; i += 256) {
        int bb = i >> 8;                    // DC_ == 256
        int d  = i & 255;
        int tb = t[b0 + bb];
        cts[i] = c[((size_t)(b0 + bb) * T_ + tb) * DC_ + d];
    }
    __syncthreads();

    const int o = oz * 256 + tid;
    const float4* W4   = (const float4*)(W + ((size_t)k * DZ_ + o) * DC_);
    const float4* cts4 = (const float4*)cts;

    float acc[8];
    #pragma unroll
    for (int bb = 0; bb < 8; ++bb) acc[bb] = 0.f;

    for (int d4 = 0; d4 < DC_ / 4; ++d4) {
        float4 w = W4[d4];
        #pragma unroll
        for (int bb = 0; bb < 8; ++bb) {
            float4 cv = cts4[bb * (DC_ / 4) + d4];   // same-address broadcast
            acc[bb] += w.x * cv.x + w.y * cv.y + w.z * cv.z + w.w * cv.w;
        }
    }

    const float bv = bias[(size_t)k * DZ_ + o];
    #pragma unroll
    for (int bb = 0; bb < 8; ++bb)
        pred[((size_t)(b0 + bb) * K_ + k) * DZ_ + o] = acc[bb] + bv;
}

// ---------------------------------------------------------------------------
// Kernel B: s[k][b][row] = z[b][row] . pred[b][k]   (the 268 MB z pass)
// grid (T/128, B); block 256 = 4 waves; each wave owns 32 rows.
// lane = r8*8 + i8: i8 indexes the d-slice (8 lanes/row), each lane
// accumulates 4 consecutive rows x 12 k in registers -> reduction is only
// 3 butterfly stages over 8 lanes, and each pred LDS read serves 4 rows.
// ---------------------------------------------------------------------------
#define WROWS   32
#define ROWS_PB 128
__global__ __launch_bounds__(256) void score_kernel(
    const float* __restrict__ z, const float* __restrict__ pred,
    float* __restrict__ s)
{
    __shared__ float ps[K_ * DZ_];          // 24 KB: pred[b][k][o]
    const int b   = blockIdx.y;
    const int tid = threadIdx.x;

    const float4* pg  = (const float4*)(pred + (size_t)b * K_ * DZ_);
    float4*       psv = (float4*)ps;
    for (int i = tid; i < K_ * DZ_ / 4; i += 256) psv[i] = pg[i];
    __syncthreads();

    const int wave = tid >> 6, lane = tid & 63;
    const int i8   = lane & 7;              // d-slice: d = it*32 + i8*4
    const int r8   = lane >> 3;             // row group within wave
    const int row0 = blockIdx.x * ROWS_PB + wave * WROWS + r8 * 4;

    const float4* zr0 = (const float4*)(z + ((size_t)b * T_ + row0) * DZ_) + i8;
    const float4* ps4 = (const float4*)ps + i8;

    float acc[4][K_];
    #pragma unroll
    for (int j = 0; j < 4; ++j)
        #pragma unroll
        for (int k = 0; k < K_; ++k) acc[j][k] = 0.f;

    #pragma unroll 2
    for (int it = 0; it < 16; ++it) {
        float4 zv[4];
        #pragma unroll
        for (int j = 0; j < 4; ++j) zv[j] = zr0[j * (DZ_ / 4) + it * 8];
        #pragma unroll
        for (int k = 0; k < K_; ++k) {
            float4 p = ps4[k * (DZ_ / 4) + it * 8];   // bcast x8, conflict-free
            #pragma unroll
            for (int j = 0; j < 4; ++j)
                acc[j][k] += zv[j].x * p.x + zv[j].y * p.y
                           + zv[j].z * p.z + zv[j].w * p.w;
        }
    }

    // reduce across the 8 d-slice lanes (xor 1,2,4 stays within the group)
    #pragma unroll
    for (int j = 0; j < 4; ++j)
        #pragma unroll
        for (int k = 0; k < K_; ++k) {
            float v = acc[j][k];
            v += __shfl_xor(v, 1, 64);
            v += __shfl_xor(v, 2, 64);
            v += __shfl_xor(v, 4, 64);
            acc[j][k] = v;
        }

    if (i8 == 0) {
        #pragma unroll
        for (int k = 0; k < K_; ++k)
            #pragma unroll
            for (int j = 0; j < 4; ++j)
                s[((size_t)k * B_ + b) * T_ + row0 + j] = acc[j][k];
    }
}

// ---------------------------------------------------------------------------
// Kernel C: per (k,b): lse over {pos} u {s[k,b,actual(k,b,r,j)]}, accumulate
// (lse - pos) / (K*B*R) into out. grid (K, B), block 256.
// ---------------------------------------------------------------------------
__global__ __launch_bounds__(256) void loss_kernel(
    const float* __restrict__ s, const int* __restrict__ t,
    const int* __restrict__ rand_idx, float* __restrict__ out)
{
    __shared__ float srow[T_];              // 8 KB score row
    __shared__ float red_m[4], red_l[4];
    const int k   = blockIdx.x;             // step = k+1
    const int b   = blockIdx.y;
    const int tid = threadIdx.x;

    const float4* sg = (const float4*)(s + ((size_t)k * B_ + b) * T_);
    float4* s4 = (float4*)srow;
    for (int i = tid; i < T_ / 4; i += 256) s4[i] = sg[i];
    __syncthreads();

    const int e   = t[b] + k + 1;
    const float pos = srow[e];
    float total = 0.f;

    for (int r = 0; r < R_; ++r) {
        const int* ri = rand_idx + ((size_t)k * R_ + r) * (T_ - 1);
        float m = -INFINITY, l = 0.f;
        for (int j = tid; j < T_ - 1; j += 256) {
            int idx = ri[j];
            idx += (idx >= e);              // skip the positive frame
            float v = srow[idx];
            if (v > m) { l = l * __expf(m - v) + 1.f; m = v; }
            else       { l += __expf(v - m); }
        }
        // wave butterfly combine of (m, l)
        const int lane = tid & 63, wave = tid >> 6;
        #pragma unroll
        for (int off = 32; off >= 1; off >>= 1) {
            float m2 = __shfl_xor(m, off, 64);
            float l2 = __shfl_xor(l, off, 64);
            float mn = fmaxf(m, m2);
            l = l * __expf(m - mn) + l2 * __expf(m2 - mn);
            m = mn;
        }
        if (lane == 0) { red_m[wave] = m; red_l[wave] = l; }
        __syncthreads();
        if (tid == 0) {
            float M = pos, L = 1.f;         // candidate 0 is the positive
            for (int w = 0; w < 4; ++w) {
                float m2 = red_m[w], l2 = red_l[w];
                float mn = fmaxf(M, m2);
                L = L * __expf(M - mn) + l2 * __expf(m2 - mn);
                M = mn;
            }
            total += (M + __logf(L)) - pos;
        }
        __syncthreads();
    }
    if (tid == 0)
        atomicAdd(out, total * (1.0f / (K_ * B_ * R_)));
}

// ---------------------------------------------------------------------------
extern "C" void kernel_launch(void* const* d_in, const int* in_sizes, int n_in,
                              void* d_out, int out_size, void* d_ws, size_t ws_size,
                              hipStream_t stream)
{
    const float* z        = (const float*)d_in[0];
    const float* c        = (const float*)d_in[1];
    const float* Wk_w     = (const float*)d_in[2];
    const float* Wk_b     = (const float*)d_in[3];
    const int*   t        = (const int*)d_in[4];
    const int*   rand_idx = (const int*)d_in[5];
    float* out = (float*)d_out;

    float* pred = (float*)d_ws;                        // B*K*DZ  = 1.57 MB
    float* s    = pred + (size_t)B_ * K_ * DZ_;        // K*B*T   = 6.29 MB

    hipMemsetAsync(d_out, 0, sizeof(float), stream);

    pred_kernel<<<dim3(2, 8, K_), 256, 0, stream>>>(c, Wk_w, Wk_b, t, pred);
    score_kernel<<<dim3(T_ / ROWS_PB, B_), 256, 0, stream>>>(z, pred, s);
    loss_kernel<<<dim3(K_, B_), 256, 0, stream>>>(s, t, rand_idx, out);
}